// Round 5
// baseline (197.745 us; speedup 1.0000x reference)
//
#include <hip/hip_runtime.h>

// LSTM text classifier: emb-gather -> LSTM(512 steps) -> FC(32->2)
//   K1 build_ptab: ptab[v] = (emb[v] @ w_ih^T + b_ih + b_hh) * gate_scale
//      (scales fold log2e so the scan uses raw v_exp_f32 / exp2)
//   K2 lstm_scan: 1 wave per batch element. lane l owns gates l and l+64.
//   R5: systolic h-broadcast. h kept valid in ALL 64 lanes (periodic-32);
//       inner product uses v_mov_dpp WAVE_ROR:1 to rotate h across lanes with
//       PRE-ROTATED per-lane weights (direction determined by runtime probe).
//       Eliminates 32 v_readlane/step (slow + SGPR-read hazards). Weights are
//       64 named scalar floats pinned via scalar "+v" asm (R4's vector-operand
//       pin was legalized through scratch memory -> slower).

#define LOG2E 1.44269504088896340736f

typedef float f32x8 __attribute__((ext_vector_type(8)));  // fallback path only

__device__ __forceinline__ float fast_rcp(float x) { return __builtin_amdgcn_rcpf(x); }
__device__ __forceinline__ float fast_exp2(float x) { return __builtin_amdgcn_exp2f(x); }

// rotate the whole 64-lane wave by 1 (DPP WAVE_ROR:1 = dpp_ctrl 0x13C)
__device__ __forceinline__ float rot1(float v) {
    return __int_as_float(__builtin_amdgcn_mov_dpp(__float_as_int(v), 0x13C, 0xF, 0xF, true));
}

// ---------------- K1: projected + prescaled embedding table ----------------
__global__ __launch_bounds__(64, 1) void build_ptab(
    const float4* __restrict__ emb4, const float4* __restrict__ wih4,
    const float* __restrict__ bih, const float* __restrict__ bhh,
    float2* __restrict__ ptab, int nrows) {
    const int lane = threadIdx.x;

    float w0[32], w1[32];
#pragma unroll
    for (int q = 0; q < 8; ++q) {
        float4 a = wih4[lane * 8 + q];
        float4 b = wih4[(lane + 64) * 8 + q];
        w0[4 * q + 0] = a.x; w0[4 * q + 1] = a.y; w0[4 * q + 2] = a.z; w0[4 * q + 3] = a.w;
        w1[4 * q + 0] = b.x; w1[4 * q + 1] = b.y; w1[4 * q + 2] = b.z; w1[4 * q + 3] = b.w;
    }
    const float bias0 = bih[lane] + bhh[lane];
    const float bias1 = bih[lane + 64] + bhh[lane + 64];
    const float s0 = -LOG2E;                                   // rows l: i,f -> sigmoid
    const float s1 = (lane < 32) ? (2.0f * LOG2E) : (-LOG2E);  // rows l+64: g tanh / o sigmoid

    for (int v = blockIdx.x; v < nrows; v += gridDim.x) {
        float a0 = bias0, a1 = bias1;
#pragma unroll
        for (int q = 0; q < 8; ++q) {
            float4 e = emb4[v * 8 + q];  // wave-uniform -> cache broadcast
            a0 = fmaf(e.x, w0[4 * q + 0], a0);
            a0 = fmaf(e.y, w0[4 * q + 1], a0);
            a0 = fmaf(e.z, w0[4 * q + 2], a0);
            a0 = fmaf(e.w, w0[4 * q + 3], a0);
            a1 = fmaf(e.x, w1[4 * q + 0], a1);
            a1 = fmaf(e.y, w1[4 * q + 1], a1);
            a1 = fmaf(e.z, w1[4 * q + 2], a1);
            a1 = fmaf(e.w, w1[4 * q + 3], a1);
        }
        ptab[v * 64 + lane] = make_float2(a0 * s0, a1 * s1);  // coalesced 512B/row
    }
}

// ---- 32x repetition helper ----
#define REP32(M) M(0) M(1) M(2) M(3) M(4) M(5) M(6) M(7) M(8) M(9) M(10) M(11) \
    M(12) M(13) M(14) M(15) M(16) M(17) M(18) M(19) M(20) M(21) M(22) M(23)    \
    M(24) M(25) M(26) M(27) M(28) M(29) M(30) M(31)

// weight declarations / rotated loads / scalar register pins
#define WDECL(N) float wa##N, wb##N;
#define WLOAD(N)                                                   \
    {                                                              \
        int _col = (lane + dir * ((N) + 1)) & 31;                  \
        wa##N = whh[lane * 32 + _col] * s0;                        \
        wb##N = whh[(lane + 64) * 32 + _col] * s1;                 \
    }
#define WPIN(N) asm volatile("" : "+v"(wa##N), "+v"(wb##N));

// one systolic inner-product slice: rotate h once, 2 fmacs with pre-rotated weights
#define RF(N)                                                      \
    _hr = rot1(_hr);                                               \
    _a0 = fmaf(_hr, wa##N, _a0);                                   \
    _a1 = fmaf(_hr, wb##N, _a1);

// one LSTM step; G0,G1 = this lane's two prescaled gate pre-activations.
// Uses kernel-scope h, c, lo, wa0..31, wb0..31. h is valid in ALL 64 lanes
// (lane l holds h_{l&31}); c likewise.
#define STEP(G0, G1)                                                           \
    do {                                                                       \
        float _a0 = (G0), _a1 = (G1);                                          \
        float _hr = h;                                                         \
        REP32(RF)                                                              \
        float _sg = fast_rcp(1.0f + fast_exp2(_a0)); /* lo: sig(i), hi: sig(f) */ \
        float _r1 = fast_rcp(1.0f + fast_exp2(_a1)); /* lo: g-form, hi: sig(o) */ \
        float _sgx = __shfl_xor(_sg, 32, 64);                                  \
        float _r1x = __shfl_xor(_r1, 32, 64);                                  \
        float _ig = lo ? _sg : _sgx;                                           \
        float _fg = lo ? _sgx : _sg;                                           \
        float _rg = lo ? _r1 : _r1x;                                           \
        float _og = lo ? _r1x : _r1;                                           \
        float _gg = fmaf(-2.0f, _rg, 1.0f); /* tanh(g) in all lanes */         \
        c = fmaf(_fg, c, _ig * _gg);                                           \
        float _th = fmaf(-2.0f, fast_rcp(1.0f + fast_exp2(c * (2.0f * LOG2E))), 1.0f); \
        h = _og * _th;                                                         \
    } while (0)

// ---------------- K2: LSTM scan, one wave per batch element ----------------
template <bool PTAB>
__global__ __launch_bounds__(64, 1) void lstm_scan(
    const int* __restrict__ x,
    const float2* __restrict__ ptab,
    const float* __restrict__ emb,
    const float* __restrict__ wih,
    const float* __restrict__ bih,
    const float* __restrict__ bhh,
    const float* __restrict__ whh,
    const float* __restrict__ fcw,
    const float* __restrict__ fcb,
    float* __restrict__ out,
    int S) {
    extern __shared__ int xrow[];
    const int b = blockIdx.x;
    const int lane = threadIdx.x;
    const bool lo = lane < 32;

    // token ids in LDS, padded so the prefetch ring never reads OOB
    for (int i = lane; i < S + 16; i += 64) xrow[i] = (i < S) ? x[(size_t)b * S + i] : 0;
    __syncthreads();

    const float s0 = -LOG2E;
    const float s1 = lo ? (2.0f * LOG2E) : (-LOG2E);

    // probe the hardware WAVE_ROR:1 direction so the weight pre-rotation can't
    // silently mismatch it (wave-uniform result)
    int dir;
    {
        int got = __builtin_amdgcn_mov_dpp(lane, 0x13C, 0xF, 0xF, true);
        dir = (got == ((lane + 1) & 63)) ? 1 : -1;
    }

    // recurrent weights, pre-rotated for the systolic schedule, prescaled,
    // held as 64 named scalars and pinned into VGPRs
    REP32(WDECL)
    REP32(WLOAD)
    REP32(WPIN)

    float h = 0.0f, c = 0.0f;  // valid in all 64 lanes (periodic-32)

    if constexpr (PTAB) {
        // p ring = pre-activations for steps t..t+3; i ring = tokens t+4..t+7
        int i0 = xrow[4], i1 = xrow[5], i2 = xrow[6], i3 = xrow[7];
        float2 p0 = ptab[(size_t)xrow[0] * 64 + lane];
        float2 p1 = ptab[(size_t)xrow[1] * 64 + lane];
        float2 p2 = ptab[(size_t)xrow[2] * 64 + lane];
        float2 p3 = ptab[(size_t)xrow[3] * 64 + lane];
        int t = 0;
        for (; t + 8 <= S; t += 4) {
            STEP(p0.x, p0.y); p0 = ptab[(size_t)i0 * 64 + lane]; i0 = xrow[t + 8];
            STEP(p1.x, p1.y); p1 = ptab[(size_t)i1 * 64 + lane]; i1 = xrow[t + 9];
            STEP(p2.x, p2.y); p2 = ptab[(size_t)i2 * 64 + lane]; i2 = xrow[t + 10];
            STEP(p3.x, p3.y); p3 = ptab[(size_t)i3 * 64 + lane]; i3 = xrow[t + 11];
        }
        if (t + 0 < S) STEP(p0.x, p0.y);
        if (t + 1 < S) STEP(p1.x, p1.y);
        if (t + 2 < S) STEP(p2.x, p2.y);
        if (t + 3 < S) STEP(p3.x, p3.y);
        if (t + 4 < S) { float2 q = ptab[(size_t)i0 * 64 + lane]; STEP(q.x, q.y); }
        if (t + 5 < S) { float2 q = ptab[(size_t)i1 * 64 + lane]; STEP(q.x, q.y); }
        if (t + 6 < S) { float2 q = ptab[(size_t)i2 * 64 + lane]; STEP(q.x, q.y); }
    } else {
        // fallback: on-the-fly input projection (workspace too small); cold path
        f32x8 wiA0, wiA1, wiB0, wiB1;
        {
            const float4* wih4 = (const float4*)wih;
#pragma unroll
            for (int q = 0; q < 4; ++q) {
                float4 a = wih4[lane * 8 + q];
                float4 bb = wih4[(lane + 64) * 8 + q];
                float* dst0 = (q < 2) ? (float*)&wiA0 : (float*)&wiA1;
                float* dst1 = (q < 2) ? (float*)&wiB0 : (float*)&wiB1;
                int o = (q & 1) * 4;
                dst0[o + 0] = a.x * s0;  dst0[o + 1] = a.y * s0;
                dst0[o + 2] = a.z * s0;  dst0[o + 3] = a.w * s0;
                dst1[o + 0] = bb.x * s1; dst1[o + 1] = bb.y * s1;
                dst1[o + 2] = bb.z * s1; dst1[o + 3] = bb.w * s1;
            }
        }
        f32x8 wiA2, wiA3, wiB2, wiB3;
        {
            const float4* wih4 = (const float4*)wih;
#pragma unroll
            for (int q = 4; q < 8; ++q) {
                float4 a = wih4[lane * 8 + q];
                float4 bb = wih4[(lane + 64) * 8 + q];
                float* dst0 = (q < 6) ? (float*)&wiA2 : (float*)&wiA3;
                float* dst1 = (q < 6) ? (float*)&wiB2 : (float*)&wiB3;
                int o = (q & 1) * 4;
                dst0[o + 0] = a.x * s0;  dst0[o + 1] = a.y * s0;
                dst0[o + 2] = a.z * s0;  dst0[o + 3] = a.w * s0;
                dst1[o + 0] = bb.x * s1; dst1[o + 1] = bb.y * s1;
                dst1[o + 2] = bb.z * s1; dst1[o + 3] = bb.w * s1;
            }
        }
        const float bias0 = (bih[lane] + bhh[lane]) * s0;
        const float bias1 = (bih[lane + 64] + bhh[lane + 64]) * s1;
        const float4* emb4 = (const float4*)emb;
        for (int t = 0; t < S; ++t) {
            int idx = xrow[t];
            float a0 = bias0, a1 = bias1;
#pragma unroll
            for (int q = 0; q < 2; ++q) {
                float4 e = emb4[(size_t)idx * 8 + q];
                a0 = fmaf(e.x, wiA0[4 * q + 0], a0); a0 = fmaf(e.y, wiA0[4 * q + 1], a0);
                a0 = fmaf(e.z, wiA0[4 * q + 2], a0); a0 = fmaf(e.w, wiA0[4 * q + 3], a0);
                a1 = fmaf(e.x, wiB0[4 * q + 0], a1); a1 = fmaf(e.y, wiB0[4 * q + 1], a1);
                a1 = fmaf(e.z, wiB0[4 * q + 2], a1); a1 = fmaf(e.w, wiB0[4 * q + 3], a1);
            }
#pragma unroll
            for (int q = 0; q < 2; ++q) {
                float4 e = emb4[(size_t)idx * 8 + 2 + q];
                a0 = fmaf(e.x, wiA1[4 * q + 0], a0); a0 = fmaf(e.y, wiA1[4 * q + 1], a0);
                a0 = fmaf(e.z, wiA1[4 * q + 2], a0); a0 = fmaf(e.w, wiA1[4 * q + 3], a0);
                a1 = fmaf(e.x, wiB1[4 * q + 0], a1); a1 = fmaf(e.y, wiB1[4 * q + 1], a1);
                a1 = fmaf(e.z, wiB1[4 * q + 2], a1); a1 = fmaf(e.w, wiB1[4 * q + 3], a1);
            }
#pragma unroll
            for (int q = 0; q < 2; ++q) {
                float4 e = emb4[(size_t)idx * 8 + 4 + q];
                a0 = fmaf(e.x, wiA2[4 * q + 0], a0); a0 = fmaf(e.y, wiA2[4 * q + 1], a0);
                a0 = fmaf(e.z, wiA2[4 * q + 2], a0); a0 = fmaf(e.w, wiA2[4 * q + 3], a0);
                a1 = fmaf(e.x, wiB2[4 * q + 0], a1); a1 = fmaf(e.y, wiB2[4 * q + 1], a1);
                a1 = fmaf(e.z, wiB2[4 * q + 2], a1); a1 = fmaf(e.w, wiB2[4 * q + 3], a1);
            }
#pragma unroll
            for (int q = 0; q < 2; ++q) {
                float4 e = emb4[(size_t)idx * 8 + 6 + q];
                a0 = fmaf(e.x, wiA3[4 * q + 0], a0); a0 = fmaf(e.y, wiA3[4 * q + 1], a0);
                a0 = fmaf(e.z, wiA3[4 * q + 2], a0); a0 = fmaf(e.w, wiA3[4 * q + 3], a0);
                a1 = fmaf(e.x, wiB3[4 * q + 0], a1); a1 = fmaf(e.y, wiB3[4 * q + 1], a1);
                a1 = fmaf(e.z, wiB3[4 * q + 2], a1); a1 = fmaf(e.w, wiB3[4 * q + 3], a1);
            }
            STEP(a0, a1);
        }
    }

    // FC: out[b][n] = sum_k h_k * fc_w[n][k] + fc_b[n]; use lanes 0..31 only
    // (h is valid in all lanes but periodic -> mask to avoid double-counting)
    float wv0 = fcw[lane & 31];
    float wv1 = fcw[32 + (lane & 31)];
    float p0v = lo ? h * wv0 : 0.0f;
    float p1v = lo ? h * wv1 : 0.0f;
#pragma unroll
    for (int m = 32; m >= 1; m >>= 1) {
        p0v += __shfl_xor(p0v, m, 64);
        p1v += __shfl_xor(p1v, m, 64);
    }
    if (lane == 0) {
        out[b * 2 + 0] = p0v + fcb[0];
        out[b * 2 + 1] = p1v + fcb[1];
    }
}

extern "C" void kernel_launch(void* const* d_in, const int* in_sizes, int n_in,
                              void* d_out, int out_size, void* d_ws, size_t ws_size,
                              hipStream_t stream) {
    const int* x = (const int*)d_in[0];
    const float* emb = (const float*)d_in[1];
    const float* wih = (const float*)d_in[2];
    const float* whh = (const float*)d_in[3];
    const float* bih = (const float*)d_in[4];
    const float* bhh = (const float*)d_in[5];
    const float* fcw = (const float*)d_in[6];
    const float* fcb = (const float*)d_in[7];
    float* out = (float*)d_out;

    const int B = out_size / 2;          // 1024
    const int S = in_sizes[0] / B;       // 512
    const int nrows = in_sizes[1] / 32;  // 50001 (EMB=32)

    const size_t need = (size_t)nrows * 64 * sizeof(float2);  // 25.6 MB
    const size_t smem = (size_t)(S + 16) * sizeof(int);

    if (ws_size >= need) {
        float2* ptab = (float2*)d_ws;
        int nb = nrows < 4096 ? nrows : 4096;
        build_ptab<<<nb, 64, 0, stream>>>((const float4*)emb, (const float4*)wih,
                                          bih, bhh, ptab, nrows);
        lstm_scan<true><<<B, 64, smem, stream>>>(x, ptab, emb, wih, bih, bhh, whh,
                                                 fcw, fcb, out, S);
    } else {
        lstm_scan<false><<<B, 64, smem, stream>>>(x, nullptr, emb, wih, bih, bhh, whh,
                                                  fcw, fcb, out, S);
    }
}

// Round 6
// 148.720 us; speedup vs baseline: 1.3296x; 1.3296x over previous
//
#include <hip/hip_runtime.h>

// LSTM text classifier: emb-gather -> LSTM(512 steps) -> FC(32->2)
//   K1 build_ptab: ptab[v] = (emb[v] @ w_ih^T + b_ih + b_hh) * gate_scale
//      (scales fold log2e so the scan uses raw v_exp_f32 / exp2)
//   K2 lstm_scan: 1 wave per batch element. lane l owns gates l and l+64.
//   R6: ROOT CAUSE of R2-R5 spills: for a 64-thread workgroup the backend
//       targets 8 waves/EU occupancy (VGPR budget 64!) and spills everything
//       past it — all pin attempts landed at VGPR 44-52 (<=64). Our grid is
//       1024 waves on 1024 SIMDs = 1 wave/SIMD, so that occupancy is useless.
//       amdgpu_waves_per_eu(1,1) sets the pressure target to 1 wave/EU
//       (512 VGPRs) -> weights stay register-resident. Structure = R3 (best).

#define LOG2E 1.44269504088896340736f

typedef float f32x32 __attribute__((ext_vector_type(32)));
typedef float f32x8 __attribute__((ext_vector_type(8)));

__device__ __forceinline__ float fast_rcp(float x) { return __builtin_amdgcn_rcpf(x); }
__device__ __forceinline__ float fast_exp2(float x) { return __builtin_amdgcn_exp2f(x); }

__device__ __forceinline__ float lane_bcast(float v, int srclane) {
    return __uint_as_float(__builtin_amdgcn_readlane(__float_as_uint(v), srclane));
}

// broadcast the HIGH 32 lanes' values to lanes 0..31 (lanes>=32 get don't-care)
// byte-identical since R2 (verified: absmax 0.0) — do not touch.
__device__ __forceinline__ float bcast_hi(float x) {
#if __has_builtin(__builtin_amdgcn_permlane32_swap)
    typedef unsigned uv2 __attribute__((ext_vector_type(2)));
    uv2 r = __builtin_amdgcn_permlane32_swap(__float_as_uint(x), __float_as_uint(x),
                                             false, false);
    return __uint_as_float(r.y);  // hi-half value delivered to lanes 0..31
#else
    return __shfl_xor(x, 32, 64);
#endif
}

// ---------------- K1: projected + prescaled embedding table ----------------
__global__ __launch_bounds__(64, 1) void build_ptab(
    const float4* __restrict__ emb4, const float4* __restrict__ wih4,
    const float* __restrict__ bih, const float* __restrict__ bhh,
    float2* __restrict__ ptab, int nrows) {
    const int lane = threadIdx.x;

    float w0[32], w1[32];
#pragma unroll
    for (int q = 0; q < 8; ++q) {
        float4 a = wih4[lane * 8 + q];
        float4 b = wih4[(lane + 64) * 8 + q];
        w0[4 * q + 0] = a.x; w0[4 * q + 1] = a.y; w0[4 * q + 2] = a.z; w0[4 * q + 3] = a.w;
        w1[4 * q + 0] = b.x; w1[4 * q + 1] = b.y; w1[4 * q + 2] = b.z; w1[4 * q + 3] = b.w;
    }
    const float bias0 = bih[lane] + bhh[lane];
    const float bias1 = bih[lane + 64] + bhh[lane + 64];
    const float s0 = -LOG2E;                                   // rows l: i,f -> sigmoid
    const float s1 = (lane < 32) ? (2.0f * LOG2E) : (-LOG2E);  // rows l+64: g tanh / o sigmoid

    for (int v = blockIdx.x; v < nrows; v += gridDim.x) {
        float a0 = bias0, a1 = bias1;
#pragma unroll
        for (int q = 0; q < 8; ++q) {
            float4 e = emb4[v * 8 + q];  // wave-uniform -> cache broadcast
            a0 = fmaf(e.x, w0[4 * q + 0], a0);
            a0 = fmaf(e.y, w0[4 * q + 1], a0);
            a0 = fmaf(e.z, w0[4 * q + 2], a0);
            a0 = fmaf(e.w, w0[4 * q + 3], a0);
            a1 = fmaf(e.x, w1[4 * q + 0], a1);
            a1 = fmaf(e.y, w1[4 * q + 1], a1);
            a1 = fmaf(e.z, w1[4 * q + 2], a1);
            a1 = fmaf(e.w, w1[4 * q + 3], a1);
        }
        ptab[v * 64 + lane] = make_float2(a0 * s0, a1 * s1);  // coalesced 512B/row
    }
}

// one LSTM step; G0,G1 are this lane's two prescaled gate pre-activations.
// Uses kernel-scope h, c, wf0, wf1. All indices compile-time.
#define STEP(G0, G1)                                                          \
    do {                                                                      \
        float _x0 = (G0), _x1 = 0.f, _x2 = 0.f, _x3 = 0.f;                    \
        float _y0 = (G1), _y1 = 0.f, _y2 = 0.f, _y3 = 0.f;                    \
        _Pragma("unroll") for (int _j = 0; _j < 32; _j += 4) {                \
            float _h0 = lane_bcast(h, _j + 0);                                \
            float _h1 = lane_bcast(h, _j + 1);                                \
            float _h2 = lane_bcast(h, _j + 2);                                \
            float _h3 = lane_bcast(h, _j + 3);                                \
            _x0 = fmaf(_h0, wf0[_j + 0], _x0);                                \
            _y0 = fmaf(_h0, wf1[_j + 0], _y0);                                \
            _x1 = fmaf(_h1, wf0[_j + 1], _x1);                                \
            _y1 = fmaf(_h1, wf1[_j + 1], _y1);                                \
            _x2 = fmaf(_h2, wf0[_j + 2], _x2);                                \
            _y2 = fmaf(_h2, wf1[_j + 2], _y2);                                \
            _x3 = fmaf(_h3, wf0[_j + 3], _x3);                                \
            _y3 = fmaf(_h3, wf1[_j + 3], _y3);                                \
        }                                                                     \
        float _a0 = (_x0 + _x1) + (_x2 + _x3); /* lo: y_i*s0, hi: y_f*s0 */   \
        float _a1 = (_y0 + _y1) + (_y2 + _y3); /* lo: y_g*s1, hi: y_o*s1 */   \
        float _sg = fast_rcp(1.0f + fast_exp2(_a0)); /* lo: i, hi: f */       \
        float _r1 = fast_rcp(1.0f + fast_exp2(_a1)); /* hi: o */              \
        float _fg = bcast_hi(_sg);                                            \
        float _og = bcast_hi(_r1);                                            \
        float _gg = fmaf(-2.0f, _r1, 1.0f); /* lo: tanh(g) */                 \
        c = fmaf(_fg, c, _sg * _gg);                                          \
        float _e2 = fast_exp2(c * (2.0f * LOG2E));                            \
        h = _og * fmaf(-2.0f, fast_rcp(1.0f + _e2), 1.0f);                    \
    } while (0)

// ---------------- K2: LSTM scan, one wave per batch element ----------------
template <bool PTAB>
__global__ __launch_bounds__(64)
__attribute__((amdgpu_waves_per_eu(1, 1)))  // pressure target = 1 wave/EU -> 512 VGPR budget
void lstm_scan(
    const int* __restrict__ x,
    const float2* __restrict__ ptab,
    const float* __restrict__ emb,
    const float* __restrict__ wih,
    const float* __restrict__ bih,
    const float* __restrict__ bhh,
    const float* __restrict__ whh,
    const float* __restrict__ fcw,
    const float* __restrict__ fcb,
    float* __restrict__ out,
    int S) {
    extern __shared__ int xrow[];
    const int b = blockIdx.x;
    const int lane = threadIdx.x;

    // token ids in LDS, padded so the prefetch ring never reads OOB
    for (int i = lane; i < S + 16; i += 64) xrow[i] = (i < S) ? x[(size_t)b * S + i] : 0;
    __syncthreads();

    const float s0 = -LOG2E;
    const float s1 = (lane < 32) ? (2.0f * LOG2E) : (-LOG2E);

    // recurrent weights: lane l holds prescaled w_hh rows l and l+64 as SSA vectors
    f32x32 wf0, wf1;
    {
        const float4* whh4 = (const float4*)whh;
#pragma unroll
        for (int q = 0; q < 8; ++q) {
            float4 a = whh4[lane * 8 + q];
            float4 bb = whh4[(lane + 64) * 8 + q];
            wf0[4 * q + 0] = a.x * s0; wf0[4 * q + 1] = a.y * s0;
            wf0[4 * q + 2] = a.z * s0; wf0[4 * q + 3] = a.w * s0;
            wf1[4 * q + 0] = bb.x * s1; wf1[4 * q + 1] = bb.y * s1;
            wf1[4 * q + 2] = bb.z * s1; wf1[4 * q + 3] = bb.w * s1;
        }
    }

    float h = 0.0f, c = 0.0f;

    if constexpr (PTAB) {
        // p ring = pre-activations for steps t..t+3; i ring = tokens t+4..t+7
        int i0 = xrow[4], i1 = xrow[5], i2 = xrow[6], i3 = xrow[7];
        float2 p0 = ptab[(size_t)xrow[0] * 64 + lane];
        float2 p1 = ptab[(size_t)xrow[1] * 64 + lane];
        float2 p2 = ptab[(size_t)xrow[2] * 64 + lane];
        float2 p3 = ptab[(size_t)xrow[3] * 64 + lane];
        int t = 0;
        for (; t + 8 <= S; t += 4) {
            STEP(p0.x, p0.y); p0 = ptab[(size_t)i0 * 64 + lane]; i0 = xrow[t + 8];
            STEP(p1.x, p1.y); p1 = ptab[(size_t)i1 * 64 + lane]; i1 = xrow[t + 9];
            STEP(p2.x, p2.y); p2 = ptab[(size_t)i2 * 64 + lane]; i2 = xrow[t + 10];
            STEP(p3.x, p3.y); p3 = ptab[(size_t)i3 * 64 + lane]; i3 = xrow[t + 11];
        }
        if (t + 0 < S) STEP(p0.x, p0.y);
        if (t + 1 < S) STEP(p1.x, p1.y);
        if (t + 2 < S) STEP(p2.x, p2.y);
        if (t + 3 < S) STEP(p3.x, p3.y);
        if (t + 4 < S) { float2 q = ptab[(size_t)i0 * 64 + lane]; STEP(q.x, q.y); }
        if (t + 5 < S) { float2 q = ptab[(size_t)i1 * 64 + lane]; STEP(q.x, q.y); }
        if (t + 6 < S) { float2 q = ptab[(size_t)i2 * 64 + lane]; STEP(q.x, q.y); }
    } else {
        // fallback: on-the-fly input projection (workspace too small); cold path
        f32x32 wi0, wi1;
        {
            const float4* wih4 = (const float4*)wih;
#pragma unroll
            for (int q = 0; q < 8; ++q) {
                float4 a = wih4[lane * 8 + q];
                float4 bb = wih4[(lane + 64) * 8 + q];
                wi0[4 * q + 0] = a.x * s0; wi0[4 * q + 1] = a.y * s0;
                wi0[4 * q + 2] = a.z * s0; wi0[4 * q + 3] = a.w * s0;
                wi1[4 * q + 0] = bb.x * s1; wi1[4 * q + 1] = bb.y * s1;
                wi1[4 * q + 2] = bb.z * s1; wi1[4 * q + 3] = bb.w * s1;
            }
        }
        const float bias0 = (bih[lane] + bhh[lane]) * s0;
        const float bias1 = (bih[lane + 64] + bhh[lane + 64]) * s1;
        const float4* emb4 = (const float4*)emb;
        for (int t = 0; t < S; ++t) {
            int idx = xrow[t];
            float a0 = bias0, a1 = bias1;
#pragma unroll
            for (int q = 0; q < 8; ++q) {
                float4 e = emb4[(size_t)idx * 8 + q];
                a0 = fmaf(e.x, wi0[4 * q + 0], a0);
                a0 = fmaf(e.y, wi0[4 * q + 1], a0);
                a0 = fmaf(e.z, wi0[4 * q + 2], a0);
                a0 = fmaf(e.w, wi0[4 * q + 3], a0);
                a1 = fmaf(e.x, wi1[4 * q + 0], a1);
                a1 = fmaf(e.y, wi1[4 * q + 1], a1);
                a1 = fmaf(e.z, wi1[4 * q + 2], a1);
                a1 = fmaf(e.w, wi1[4 * q + 3], a1);
            }
            STEP(a0, a1);
        }
    }

    // FC: out[b][n] = sum_k h_k * fc_w[n][k] + fc_b[n]; h valid in lanes 0..31
    float wv0 = fcw[lane & 31];
    float wv1 = fcw[32 + (lane & 31)];
    float p0v = (lane < 32) ? h * wv0 : 0.0f;
    float p1v = (lane < 32) ? h * wv1 : 0.0f;
#pragma unroll
    for (int m = 32; m >= 1; m >>= 1) {
        p0v += __shfl_xor(p0v, m, 64);
        p1v += __shfl_xor(p1v, m, 64);
    }
    if (lane == 0) {
        out[b * 2 + 0] = p0v + fcb[0];
        out[b * 2 + 1] = p1v + fcb[1];
    }
}

extern "C" void kernel_launch(void* const* d_in, const int* in_sizes, int n_in,
                              void* d_out, int out_size, void* d_ws, size_t ws_size,
                              hipStream_t stream) {
    const int* x = (const int*)d_in[0];
    const float* emb = (const float*)d_in[1];
    const float* wih = (const float*)d_in[2];
    const float* whh = (const float*)d_in[3];
    const float* bih = (const float*)d_in[4];
    const float* bhh = (const float*)d_in[5];
    const float* fcw = (const float*)d_in[6];
    const float* fcb = (const float*)d_in[7];
    float* out = (float*)d_out;

    const int B = out_size / 2;          // 1024
    const int S = in_sizes[0] / B;       // 512
    const int nrows = in_sizes[1] / 32;  // 50001 (EMB=32)

    const size_t need = (size_t)nrows * 64 * sizeof(float2);  // 25.6 MB
    const size_t smem = (size_t)(S + 16) * sizeof(int);

    if (ws_size >= need) {
        float2* ptab = (float2*)d_ws;
        int nb = nrows < 4096 ? nrows : 4096;
        build_ptab<<<nb, 64, 0, stream>>>((const float4*)emb, (const float4*)wih,
                                          bih, bhh, ptab, nrows);
        lstm_scan<true><<<B, 64, smem, stream>>>(x, ptab, emb, wih, bih, bhh, whh,
                                                 fcw, fcb, out, S);
    } else {
        lstm_scan<false><<<B, 64, smem, stream>>>(x, nullptr, emb, wih, bih, bhh, whh,
                                                  fcw, fcb, out, S);
    }
}